// Round 5
// baseline (641.712 us; speedup 1.0000x reference)
//
#include <hip/hip_runtime.h>
#include <stdint.h>

#define S_ 1024
#define B_ 8
#define D_ 1024
#define H_ 16
#define DK_ 64
#define F_ 4096
#define EPS_ 1e-5f

typedef __bf16 bf16_t;
typedef __attribute__((ext_vector_type(8))) __bf16 bf16x8;
typedef __attribute__((ext_vector_type(4))) __bf16 bf16x4;
typedef __attribute__((ext_vector_type(4))) float f32x4;

// async global->LDS, 16B per lane; LDS dest must be wave-uniform base + lane*16
#define GLD16(gp, lp) __builtin_amdgcn_global_load_lds( \
    (__attribute__((address_space(1))) void*)(void*)(gp), \
    (__attribute__((address_space(3))) void*)(lp), 16, 0, 0)

#define BAR() __builtin_amdgcn_s_barrier()
#define SB0() __builtin_amdgcn_sched_barrier(0)
#define LG0() do { asm volatile("s_waitcnt lgkmcnt(0)" ::: "memory"); SB0(); } while (0)
#define VM6() asm volatile("s_waitcnt vmcnt(6)" ::: "memory")
#define VM4() asm volatile("s_waitcnt vmcnt(4)" ::: "memory")
#define VM3() asm volatile("s_waitcnt vmcnt(3)" ::: "memory")

// ---------------------------------------------------------------------------
// 8-phase 256x256 GEMM (T2+T3+T4+T5), C = A[M,K] * Bt[N,K]^T + bias.
// 512 threads = 8 waves (2 row-groups x 4 col-groups); per-wave 128x64 out.
// MODE 0: scatter to q/k bufs [B,H,S,DK] (col<1024 -> out/bias, else out2/bias2)
// MODE 1: relu -> bf16 row-major (ldc)
// ---------------------------------------------------------------------------
template<int MODE>
__global__ __launch_bounds__(512, 2)
void gemm8p(const bf16_t* __restrict__ A, const bf16_t* __restrict__ Bt,
            const float* __restrict__ bias, const float* __restrict__ bias2,
            void* __restrict__ out, void* __restrict__ out2,
            int K, int lda, int ldb, int ldc)
{
    __shared__ __align__(16) bf16_t AsL[2][256][64];
    __shared__ __align__(16) bf16_t BsL[2][256][64];

    const int nwg = gridDim.x * gridDim.y;
    int flat = blockIdx.y * gridDim.x + blockIdx.x;
    flat = (flat & 7) * (nwg >> 3) + (flat >> 3);
    const int bx = flat % gridDim.x, by = flat / gridDim.x;
    const int rowBase = by * 256, colBase = bx * 256;

    const int tid = threadIdx.x;
    const int lane = tid & 63;
    const int wave = tid >> 6;
    const int wr = wave >> 2, wc = wave & 3;
    const int lr = lane & 15, quad = lane >> 4;

    const int r0 = tid >> 3, r1 = 64 + r0;
    const int cs = (tid & 7) ^ (r0 & 7);
    const int cl = tid & 7;
    const bf16_t* a0p = A + (size_t)(rowBase + r0) * lda + cs * 8;
    const bf16_t* a1p = A + (size_t)(rowBase + r1) * lda + cs * 8;
    const bf16_t* b0p = Bt + (size_t)(colBase + r0) * ldb + cs * 8;
    const bf16_t* b1p = Bt + (size_t)(colBase + r1) * ldb + cs * 8;

#define STAGE_A(buf, h, kel) do { \
    GLD16(a0p + (size_t)(h) * 128 * lda + (kel), &AsL[buf][(h) * 128 + r0][cl * 8]); \
    GLD16(a1p + (size_t)(h) * 128 * lda + (kel), &AsL[buf][(h) * 128 + r1][cl * 8]); } while (0)
#define STAGE_B(buf, h, kel) do { \
    GLD16(b0p + (size_t)(h) * 128 * ldb + (kel), &BsL[buf][(h) * 128 + r0][cl * 8]); \
    GLD16(b1p + (size_t)(h) * 128 * ldb + (kel), &BsL[buf][(h) * 128 + r1][cl * 8]); } while (0)

#define RDA(buf, qm, AF) do { \
    _Pragma("unroll") for (int mi = 0; mi < 4; ++mi) { \
        const int r_ = (qm) * 128 + wr * 64 + mi * 16 + lr; \
        _Pragma("unroll") for (int kk = 0; kk < 2; ++kk) \
            AF[mi * 2 + kk] = *(const bf16x8*)&AsL[buf][r_][((kk * 4 + quad) ^ (lr & 7)) * 8]; } } while (0)
#define RDB(buf, qn, BF) do { \
    _Pragma("unroll") for (int ni = 0; ni < 2; ++ni) { \
        const int r_ = (qn) * 128 + wc * 32 + ni * 16 + lr; \
        _Pragma("unroll") for (int kk = 0; kk < 2; ++kk) \
            BF[ni * 2 + kk] = *(const bf16x8*)&BsL[buf][r_][((kk * 4 + quad) ^ (lr & 7)) * 8]; } } while (0)

#define MQ(qm, qn, AF, BF) do { \
    __builtin_amdgcn_s_setprio(1); \
    _Pragma("unroll") for (int kk = 0; kk < 2; ++kk) \
    _Pragma("unroll") for (int mi = 0; mi < 4; ++mi) \
    _Pragma("unroll") for (int ni = 0; ni < 2; ++ni) \
        acc[(qm) * 4 + mi][(qn) * 2 + ni] = __builtin_amdgcn_mfma_f32_16x16x32_bf16( \
            AF[mi * 2 + kk], BF[ni * 2 + kk], acc[(qm) * 4 + mi][(qn) * 2 + ni], 0, 0, 0); \
    __builtin_amdgcn_s_setprio(0); } while (0)

    f32x4 acc[8][4] = {};
    bf16x8 af[8], bq0[4], bq1[4];

    STAGE_A(0, 0, 0); STAGE_B(0, 0, 0); STAGE_B(0, 1, 0); STAGE_A(0, 1, 0);
    STAGE_A(1, 0, 64); STAGE_B(1, 0, 64); STAGE_B(1, 1, 64);
    VM6();
    BAR(); SB0();

    const int NT = K >> 6;
    const int kCap = K - 64;
    for (int it = 0; it < (NT >> 1); ++it) {
        const int kP1 = it * 128 + 64;
        int kN0 = it * 128 + 128; if (kN0 > kCap) kN0 = kCap;
        int kN1 = it * 128 + 192; if (kN1 > kCap) kN1 = kCap;

        // P1: T0 Q00
        RDA(0, 0, af); RDB(0, 0, bq0);
        STAGE_A(1, 1, kP1);
        BAR(); LG0();
        MQ(0, 0, af, bq0);
        BAR(); SB0();
        // P2: T0 Q01
        RDB(0, 1, bq1);
        STAGE_A(0, 0, kN0);
        BAR(); LG0();
        MQ(0, 1, af, bq1);
        BAR(); SB0();
        // P3: T0 Q11
        RDA(0, 1, af);
        STAGE_B(0, 0, kN0);
        BAR(); LG0();
        MQ(1, 1, af, bq1);
        BAR(); SB0();
        // P4: T0 Q10
        STAGE_B(0, 1, kN0);
        BAR(); SB0();
        MQ(1, 0, af, bq0);
        VM6();
        BAR(); SB0();
        // P5: T1 Q00
        RDA(1, 0, af); RDB(1, 0, bq0);
        STAGE_A(0, 1, kN0);
        BAR(); LG0();
        MQ(0, 0, af, bq0);
        BAR(); SB0();
        // P6: T1 Q01
        RDB(1, 1, bq1);
        STAGE_A(1, 0, kN1);
        BAR(); LG0();
        MQ(0, 1, af, bq1);
        BAR(); SB0();
        // P7: T1 Q11
        RDA(1, 1, af);
        STAGE_B(1, 0, kN1);
        BAR(); LG0();
        MQ(1, 1, af, bq1);
        BAR(); SB0();
        // P8: T1 Q10
        STAGE_B(1, 1, kN1);
        BAR(); SB0();
        MQ(1, 0, af, bq0);
        VM6();
        BAR(); SB0();
    }

#pragma unroll
    for (int mi = 0; mi < 8; ++mi) {
#pragma unroll
        for (int ni = 0; ni < 4; ++ni) {
            const int col = colBase + (ni >> 1) * 128 + wc * 32 + (ni & 1) * 16 + lr;
            float bv;
            if constexpr (MODE == 0) bv = (col < 1024) ? bias[col] : bias2[col - 1024];
            else bv = bias[col];
#pragma unroll
            for (int e = 0; e < 4; ++e) {
                const int row = rowBase + (mi >> 2) * 128 + wr * 64 + (mi & 3) * 16 + quad * 4 + e;
                const float v = acc[mi][ni][e] + bv;
                if constexpr (MODE == 0) {
                    const int sel = col >> 10, c10 = col & 1023;
                    const int s = row >> 3, b = row & 7, h = c10 >> 6, dk = c10 & 63;
                    bf16_t* dst = sel ? (bf16_t*)out2 : (bf16_t*)out;
                    dst[(((size_t)(b * 16 + h) * 1024 + s) << 6) + dk] = (bf16_t)v;
                } else {
                    ((bf16_t*)out)[(size_t)row * ldc + col] = (bf16_t)fmaxf(v, 0.f);
                }
            }
        }
    }
#undef STAGE_A
#undef STAGE_B
#undef RDA
#undef RDB
#undef MQ
}

// ---------------------------------------------------------------------------
// 4-phase 256x128 GEMM, same technique stack, for N=1024 shapes (grid 256).
// MODE 0: fp32 out row-major (ldc)
// MODE 2: bf16 out scattered to vt buf [B,H,DK,S]
// ---------------------------------------------------------------------------
template<int MODE>
__global__ __launch_bounds__(512, 2)
void gemm4p(const bf16_t* __restrict__ A, const bf16_t* __restrict__ Bt,
            const float* __restrict__ bias, void* __restrict__ out,
            int K, int lda, int ldb, int ldc)
{
    __shared__ __align__(16) bf16_t AsL[2][256][64];
    __shared__ __align__(16) bf16_t BsL[2][128][64];

    const int nwg = gridDim.x * gridDim.y;
    int flat = blockIdx.y * gridDim.x + blockIdx.x;
    flat = (flat & 7) * (nwg >> 3) + (flat >> 3);
    const int bx = flat % gridDim.x, by = flat / gridDim.x;
    const int rowBase = by * 256, colBase = bx * 128;

    const int tid = threadIdx.x;
    const int lane = tid & 63;
    const int wave = tid >> 6;
    const int wr = wave >> 2, wc = wave & 3;
    const int lr = lane & 15, quad = lane >> 4;

    const int r0 = tid >> 3, r1 = 64 + r0;
    const int cs = (tid & 7) ^ (r0 & 7);
    const int cl = tid & 7;
    const bf16_t* a0p = A + (size_t)(rowBase + r0) * lda + cs * 8;
    const bf16_t* a1p = A + (size_t)(rowBase + r1) * lda + cs * 8;
    const bf16_t* b0p = Bt + (size_t)(colBase + r0) * ldb + cs * 8;

#define STAGE_A(buf, h, kel) do { \
    GLD16(a0p + (size_t)(h) * 128 * lda + (kel), &AsL[buf][(h) * 128 + r0][cl * 8]); \
    GLD16(a1p + (size_t)(h) * 128 * lda + (kel), &AsL[buf][(h) * 128 + r1][cl * 8]); } while (0)
#define STAGE_B(buf, h, kel) \
    GLD16(b0p + (size_t)(h) * 64 * ldb + (kel), &BsL[buf][(h) * 64 + r0][cl * 8])

#define RDA(buf, qm, AF) do { \
    _Pragma("unroll") for (int mi = 0; mi < 4; ++mi) { \
        const int r_ = (qm) * 128 + wr * 64 + mi * 16 + lr; \
        _Pragma("unroll") for (int kk = 0; kk < 2; ++kk) \
            AF[mi * 2 + kk] = *(const bf16x8*)&AsL[buf][r_][((kk * 4 + quad) ^ (lr & 7)) * 8]; } } while (0)
#define RDBF(buf, BQ) do { \
    _Pragma("unroll") for (int qn = 0; qn < 2; ++qn) { \
        const int r_ = qn * 64 + wc * 16 + lr; \
        _Pragma("unroll") for (int kk = 0; kk < 2; ++kk) \
            BQ[qn * 2 + kk] = *(const bf16x8*)&BsL[buf][r_][((kk * 4 + quad) ^ (lr & 7)) * 8]; } } while (0)

#define MQA(qm) do { \
    __builtin_amdgcn_s_setprio(1); \
    _Pragma("unroll") for (int kk = 0; kk < 2; ++kk) \
    _Pragma("unroll") for (int mi = 0; mi < 4; ++mi) \
    _Pragma("unroll") for (int qn = 0; qn < 2; ++qn) \
        acc[(qm) * 4 + mi][qn] = __builtin_amdgcn_mfma_f32_16x16x32_bf16( \
            af[mi * 2 + kk], bq[qn * 2 + kk], acc[(qm) * 4 + mi][qn], 0, 0, 0); \
    __builtin_amdgcn_s_setprio(0); } while (0)

    f32x4 acc[8][2] = {};
    bf16x8 af[8], bq[4];

    STAGE_A(0, 0, 0); STAGE_B(0, 0, 0); STAGE_B(0, 1, 0); STAGE_A(0, 1, 0);
    STAGE_A(1, 0, 64); STAGE_B(1, 0, 64); STAGE_B(1, 1, 64);
    VM4();
    BAR(); SB0();

    const int NT = K >> 6;
    const int kCap = K - 64;
    for (int it = 0; it < (NT >> 1); ++it) {
        const int kP1 = it * 128 + 64;
        int kN0 = it * 128 + 128; if (kN0 > kCap) kN0 = kCap;
        int kN1 = it * 128 + 192; if (kN1 > kCap) kN1 = kCap;

        // P1: buf0 qm0
        RDA(0, 0, af); RDBF(0, bq);
        STAGE_A(1, 1, kP1);
        BAR(); LG0();
        MQA(0);
        BAR(); SB0();
        // P2: buf0 qm1
        RDA(0, 1, af);
        STAGE_A(0, 0, kN0); STAGE_B(0, 0, kN0);
        BAR(); LG0();
        MQA(1);
        VM3();
        BAR(); SB0();
        // P3: buf1 qm0
        RDA(1, 0, af); RDBF(1, bq);
        STAGE_B(0, 1, kN0); STAGE_A(0, 1, kN0);
        BAR(); LG0();
        MQA(0);
        BAR(); SB0();
        // P4: buf1 qm1
        RDA(1, 1, af);
        STAGE_A(1, 0, kN1); STAGE_B(1, 0, kN1); STAGE_B(1, 1, kN1);
        BAR(); LG0();
        MQA(1);
        VM4();
        BAR(); SB0();
    }

#pragma unroll
    for (int mi = 0; mi < 8; ++mi) {
#pragma unroll
        for (int ni = 0; ni < 2; ++ni) {
            const int col = colBase + ni * 64 + wc * 16 + lr;
            const float bv = bias[col];
#pragma unroll
            for (int e = 0; e < 4; ++e) {
                const int row = rowBase + (mi >> 2) * 128 + wr * 64 + (mi & 3) * 16 + quad * 4 + e;
                const float v = acc[mi][ni][e] + bv;
                if constexpr (MODE == 0) {
                    ((float*)out)[(size_t)row * ldc + col] = v;
                } else {
                    const int s = row >> 3, b = row & 7, h = col >> 6, dk = col & 63;
                    ((bf16_t*)out)[(((size_t)(b * 16 + h) * 64 + dk) << 10) + s] = (bf16_t)v;
                }
            }
        }
    }
#undef STAGE_A
#undef STAGE_B
#undef RDA
#undef RDBF
#undef MQA
}

// ---------------------------------------------------------------------------
// Fused attention: per block = one (b,h) z and 16 query rows (32KB Psh,
// ~3 blocks/CU). Nontemporal attn writes keep K/V L2-resident.
// ---------------------------------------------------------------------------
__global__ __launch_bounds__(256)
void fused_attn(const bf16_t* __restrict__ qb, const bf16_t* __restrict__ kb,
                const bf16_t* __restrict__ vt, float* __restrict__ attn,
                bf16_t* __restrict__ ctx)
{
    __shared__ __align__(16) bf16_t Psh[16 * 1024];   // 32 KB, XOR-swizzled
    __shared__ float smax[4][16];
    __shared__ float ssum[4][16];

    // 8192 blocks; XCD-bijective swizzle
    int flat = blockIdx.y * 64 + blockIdx.x;
    flat = (flat & 7) * 1024 + (flat >> 3);
    const int z = flat >> 6;                 // (b*16+h)
    const int qBase = (flat & 63) * 16;
    const int b = z >> 4, h = z & 15;
    const int tid = threadIdx.x;
    const int wave = tid >> 6, lane = tid & 63;
    const int lr = lane & 15, quad = lane >> 4;

    const bf16_t* Qz = qb + ((size_t)z << 16);   // [1024][64]
    const bf16_t* Kz = kb + ((size_t)z << 16);   // [1024][64]
    const bf16_t* Vz = vt + ((size_t)z << 16);   // [64][1024]
    float* Az = attn + ((size_t)z << 20);

    // Q fragments (B-operand): n=q̂=lr, k-elems dk=kk*32+quad*8+j
    bf16x8 qf[2];
#pragma unroll
    for (int kk = 0; kk < 2; ++kk)
        qf[kk] = *(const bf16x8*)(Qz + (size_t)(qBase + lr) * 64 + kk * 32 + quad * 8);

    // scores^T: C row m = k_t (this wave's 256-slice), col n = q̂
    f32x4 acc[16] = {};
#pragma unroll
    for (int mi = 0; mi < 16; ++mi) {
        const bf16_t* kp = Kz + (size_t)(wave * 256 + mi * 16 + lr) * 64 + quad * 8;
        bf16x8 kf0 = *(const bf16x8*)kp;
        bf16x8 kf1 = *(const bf16x8*)(kp + 32);
        acc[mi] = __builtin_amdgcn_mfma_f32_16x16x32_bf16(kf0, qf[0], acc[mi], 0, 0, 0);
        acc[mi] = __builtin_amdgcn_mfma_f32_16x16x32_bf16(kf1, qf[1], acc[mi], 0, 0, 0);
    }

    // per-q̂ raw max over this wave's 256 k's
    {
        float mx = acc[0][0];
#pragma unroll
        for (int mi = 0; mi < 16; ++mi)
            mx = fmaxf(mx, fmaxf(fmaxf(acc[mi][0], acc[mi][1]),
                                 fmaxf(acc[mi][2], acc[mi][3])));
        mx = fmaxf(mx, __shfl_xor(mx, 16, 64));
        mx = fmaxf(mx, __shfl_xor(mx, 32, 64));
        if (quad == 0) smax[wave][lr] = mx;
    }
    __syncthreads();

    {
        const float mm = 0.125f * fmaxf(fmaxf(smax[0][lr], smax[1][lr]),
                                        fmaxf(smax[2][lr], smax[3][lr]));
        float s = 0.f;
#pragma unroll
        for (int mi = 0; mi < 16; ++mi)
#pragma unroll
            for (int e = 0; e < 4; ++e) {
                float p = __expf(fmaf(acc[mi][e], 0.125f, -mm));
                acc[mi][e] = p; s += p;
            }
        s += __shfl_xor(s, 16, 64);
        s += __shfl_xor(s, 32, 64);
        if (quad == 0) ssum[wave][lr] = s;
    }
    __syncthreads();

    {
        const float r = 1.0f / (ssum[0][lr] + ssum[1][lr] + ssum[2][lr] + ssum[3][lr]);
        float* arow = Az + ((size_t)(qBase + lr) << 10);
#pragma unroll
        for (int mi = 0; mi < 16; ++mi) {
            const int k0 = wave * 256 + mi * 16 + quad * 4;   // 4 consecutive k per lane
            f32x4 o;
            o[0] = acc[mi][0] * r; o[1] = acc[mi][1] * r;
            o[2] = acc[mi][2] * r; o[3] = acc[mi][3] * r;
            __builtin_nontemporal_store(o, (f32x4*)(arow + k0)); // write-once stream
            bf16x4 pb;
            pb[0] = (bf16_t)o[0]; pb[1] = (bf16_t)o[1]; pb[2] = (bf16_t)o[2]; pb[3] = (bf16_t)o[3];
            int byte = lr * 2048 + k0 * 2;
            byte ^= (lr & 7) << 4;                             // bank-conflict swizzle
            *(bf16x4*)((char*)Psh + byte) = pb;
        }
    }
    __syncthreads();

    // PV: wave owns d-cols [wave*16, wave*16+16); A from swizzled Psh, B from L2
    f32x4 cacc = {};
#pragma unroll
    for (int kt = 0; kt < 32; ++kt) {
        bf16x8 vf = *(const bf16x8*)(Vz + (size_t)(wave * 16 + lr) * 1024 + kt * 32 + quad * 8);
        int byte = lr * 2048 + (kt * 32 + quad * 8) * 2;
        byte ^= (lr & 7) << 4;
        bf16x8 af = *(const bf16x8*)((const char*)Psh + byte);
        cacc = __builtin_amdgcn_mfma_f32_16x16x32_bf16(af, vf, cacc, 0, 0, 0);
    }
#pragma unroll
    for (int e = 0; e < 4; ++e) {
        const int s = qBase + quad * 4 + e;
        ctx[(((size_t)s * 8 + b) << 10) + h * 64 + wave * 16 + lr] = (bf16_t)cacc[e];
    }
}

__global__ __launch_bounds__(256)
void prep_kernel(const float* __restrict__ src, const float* __restrict__ pos,
                 bf16_t* __restrict__ qk, bf16_t* __restrict__ vv)
{
    const size_t i = ((size_t)blockIdx.x * 256 + threadIdx.x) * 4;
    float4 s = *(const float4*)(src + i);
    float4 q = *(const float4*)(pos + i);
    bf16x4 qo, vo;
    qo[0] = (bf16_t)(s.x + q.x); qo[1] = (bf16_t)(s.y + q.y);
    qo[2] = (bf16_t)(s.z + q.z); qo[3] = (bf16_t)(s.w + q.w);
    vo[0] = (bf16_t)s.x; vo[1] = (bf16_t)s.y; vo[2] = (bf16_t)s.z; vo[3] = (bf16_t)s.w;
    *(bf16x4*)(qk + i) = qo;
    *(bf16x4*)(vv + i) = vo;
}

// z-batched: four 1024x1024 fp32 W -> bf16 WT [N,K]
__global__ __launch_bounds__(256)
void transpose_w4(const float* __restrict__ W0, const float* __restrict__ W1,
                  const float* __restrict__ W2, const float* __restrict__ W3,
                  bf16_t* __restrict__ T0, bf16_t* __restrict__ T1,
                  bf16_t* __restrict__ T2, bf16_t* __restrict__ T3)
{
    __shared__ float t[32][33];
    const float* W; bf16_t* T;
    switch (blockIdx.z) {
        case 0: W = W0; T = T0; break;
        case 1: W = W1; T = T1; break;
        case 2: W = W2; T = T2; break;
        default: W = W3; T = T3; break;
    }
    const int n0 = blockIdx.x * 32, k0 = blockIdx.y * 32;
    const int tx = threadIdx.x & 31;
    const int ty = threadIdx.x >> 5;
#pragma unroll
    for (int j = 0; j < 32; j += 8)
        t[ty + j][tx] = W[(size_t)(k0 + ty + j) * 1024 + n0 + tx];
    __syncthreads();
#pragma unroll
    for (int j = 0; j < 32; j += 8)
        T[(size_t)(n0 + ty + j) * 1024 + k0 + tx] = (bf16_t)t[tx][ty + j];
}

// W fp32 [K,N] row-major -> WT bf16 [N,K]
__global__ __launch_bounds__(256)
void transpose_w(const float* __restrict__ W, bf16_t* __restrict__ WT, int K, int N)
{
    __shared__ float t[32][33];
    const int n0 = blockIdx.x * 32, k0 = blockIdx.y * 32;
    const int tx = threadIdx.x & 31;
    const int ty = threadIdx.x >> 5;
#pragma unroll
    for (int j = 0; j < 32; j += 8)
        t[ty + j][tx] = W[(size_t)(k0 + ty + j) * N + n0 + tx];
    __syncthreads();
#pragma unroll
    for (int j = 0; j < 32; j += 8)
        WT[(size_t)(n0 + ty + j) * K + k0 + tx] = (bf16_t)t[tx][ty + j];
}

// LN over D=1024 of (a+b); writes any of xf (fp32), xb (bf16), outf (fp32)
__global__ __launch_bounds__(256)
void ln_kernel(const float* __restrict__ a, const float* __restrict__ b,
               const float* __restrict__ g, const float* __restrict__ be,
               float* __restrict__ xf, bf16_t* __restrict__ xb, float* __restrict__ outf)
{
    __shared__ float sh[8];
    const int r = blockIdx.x;
    const int t = threadIdx.x;
    float4 va = ((const float4*)(a + ((size_t)r << 10)))[t];
    float4 vb = ((const float4*)(b + ((size_t)r << 10)))[t];
    float x0 = va.x + vb.x, x1 = va.y + vb.y, x2 = va.z + vb.z, x3 = va.w + vb.w;
    float s = x0 + x1 + x2 + x3;
    float sq = x0 * x0 + x1 * x1 + x2 * x2 + x3 * x3;
#pragma unroll
    for (int o = 32; o > 0; o >>= 1) { s += __shfl_xor(s, o, 64); sq += __shfl_xor(sq, o, 64); }
    const int w = t >> 6, ln = t & 63;
    if (ln == 0) { sh[w] = s; sh[4 + w] = sq; }
    __syncthreads();
    s = sh[0] + sh[1] + sh[2] + sh[3];
    sq = sh[4] + sh[5] + sh[6] + sh[7];
    const float mean = s * (1.f / 1024.f);
    const float var = sq * (1.f / 1024.f) - mean * mean;
    const float rstd = rsqrtf(var + EPS_);
    float4 vg = ((const float4*)g)[t];
    float4 vbe = ((const float4*)be)[t];
    float y0 = (x0 - mean) * rstd * vg.x + vbe.x;
    float y1 = (x1 - mean) * rstd * vg.y + vbe.y;
    float y2 = (x2 - mean) * rstd * vg.z + vbe.z;
    float y3 = (x3 - mean) * rstd * vg.w + vbe.w;
    if (xf) { float4 o4 = {y0, y1, y2, y3}; ((float4*)(xf + ((size_t)r << 10)))[t] = o4; }
    if (xb) {
        bf16x4 ob; ob[0] = (bf16_t)y0; ob[1] = (bf16_t)y1; ob[2] = (bf16_t)y2; ob[3] = (bf16_t)y3;
        ((bf16x4*)(xb + ((size_t)r << 10)))[t] = ob;
    }
    if (outf) { float4 o4 = {y0, y1, y2, y3}; ((float4*)(outf + ((size_t)r << 10)))[t] = o4; }
}

extern "C" void kernel_launch(void* const* d_in, const int* in_sizes, int n_in,
                              void* d_out, int out_size, void* d_ws, size_t ws_size,
                              hipStream_t stream)
{
    (void)in_sizes; (void)n_in; (void)out_size; (void)ws_size;
    const float* src = (const float*)d_in[0];
    const float* pos = (const float*)d_in[1];
    const float* Wq  = (const float*)d_in[2];
    const float* bq  = (const float*)d_in[3];
    const float* Wk  = (const float*)d_in[4];
    const float* bk  = (const float*)d_in[5];
    const float* Wv  = (const float*)d_in[6];
    const float* bv  = (const float*)d_in[7];
    const float* Wo  = (const float*)d_in[8];
    const float* bo  = (const float*)d_in[9];
    const float* W1  = (const float*)d_in[10];
    const float* b1  = (const float*)d_in[11];
    const float* W2  = (const float*)d_in[12];
    const float* b2  = (const float*)d_in[13];
    const float* g1  = (const float*)d_in[14];
    const float* be1 = (const float*)d_in[15];
    const float* g2  = (const float*)d_in[16];
    const float* be2 = (const float*)d_in[17];

    float* outF  = (float*)d_out;                       // [S,B,D]
    float* attnF = outF + (size_t)S_ * B_ * D_;         // [B,H,S,S]

    char* ws = (char*)d_ws;
    size_t off = 0;
    auto alloc = [&](size_t bytes) { void* p = ws + off; off += (bytes + 255) & ~(size_t)255; return p; };

    bf16_t* qk_bf = (bf16_t*)alloc((size_t)8192 * 1024 * 2);
    bf16_t* v_bf  = (bf16_t*)alloc((size_t)8192 * 1024 * 2);
    bf16_t* wqT   = (bf16_t*)alloc((size_t)1024 * 1024 * 2);   // wqT/wkT contiguous ->
    bf16_t* wkT   = (bf16_t*)alloc((size_t)1024 * 1024 * 2);   // one [2048,1024] B for QK
    bf16_t* wvT   = (bf16_t*)alloc((size_t)1024 * 1024 * 2);
    bf16_t* woT   = (bf16_t*)alloc((size_t)1024 * 1024 * 2);
    bf16_t* w1T   = (bf16_t*)alloc((size_t)4096 * 1024 * 2);
    bf16_t* w2T   = (bf16_t*)alloc((size_t)1024 * 4096 * 2);
    bf16_t* qbuf  = (bf16_t*)alloc((size_t)8 * 16 * 1024 * 64 * 2);
    bf16_t* kbuf  = (bf16_t*)alloc((size_t)8 * 16 * 1024 * 64 * 2);
    bf16_t* vtbuf = (bf16_t*)alloc((size_t)8 * 16 * 64 * 1024 * 2);
    bf16_t* ctx_bf= (bf16_t*)alloc((size_t)8192 * 1024 * 2);
    float*  ao_f  = (float*)alloc((size_t)8192 * 1024 * 4);
    float*  x_f   = (float*)alloc((size_t)8192 * 1024 * 4);
    bf16_t* x_bf  = (bf16_t*)alloc((size_t)8192 * 1024 * 2);
    bf16_t* h_bf  = (bf16_t*)alloc((size_t)8192 * 4096 * 2);
    float*  y_f   = (float*)alloc((size_t)8192 * 1024 * 4);

    // weights -> bf16 transposed [N,K]
    transpose_w4<<<dim3(32, 32, 4), 256, 0, stream>>>(Wq, Wk, Wv, Wo, wqT, wkT, wvT, woT);
    transpose_w<<<dim3(128, 32), 256, 0, stream>>>(W1, w1T, 1024, 4096);
    transpose_w<<<dim3(32, 128), 256, 0, stream>>>(W2, w2T, 4096, 1024);

    prep_kernel<<<8192, 256, 0, stream>>>(src, pos, qk_bf, v_bf);

    // Q+K combined projection (8-phase 256^2): N=2048 over [wqT;wkT]
    gemm8p<0><<<dim3(8, 32), 512, 0, stream>>>(qk_bf, wqT, bq, bk, qbuf, kbuf, 1024, 1024, 1024, 0);
    // V projection (4-phase 256x128)
    gemm4p<2><<<dim3(8, 32), 512, 0, stream>>>(v_bf, wvT, bv, vtbuf, 1024, 1024, 1024, 0);

    // fused scores -> softmax -> attn write (NT) -> PV
    fused_attn<<<dim3(64, 128), 256, 0, stream>>>(qbuf, kbuf, vtbuf, attnF, ctx_bf);

    // attn_out = ctx @ Wo + bo (4-phase 256x128)
    gemm4p<0><<<dim3(8, 32), 512, 0, stream>>>(ctx_bf, woT, bo, ao_f, 1024, 1024, 1024, 1024);

    // x = LN(src + attn_out)
    ln_kernel<<<8192, 256, 0, stream>>>(src, ao_f, g1, be1, x_f, x_bf, nullptr);

    // ffn: h = relu(x @ W1 + b1)  (8-phase 256^2)
    gemm8p<1><<<dim3(16, 32), 512, 0, stream>>>(x_bf, w1T, b1, nullptr, h_bf, nullptr, 1024, 1024, 1024, 4096);
    // y = h @ W2 + b2 (4-phase 256x128, K=4096)
    gemm4p<0><<<dim3(8, 32), 512, 0, stream>>>(h_bf, w2T, b2, y_f, 4096, 4096, 4096, 1024);

    // out = LN(x + ffn)
    ln_kernel<<<8192, 256, 0, stream>>>(x_f, y_f, g2, be2, nullptr, nullptr, outF);
}

// Round 6
// 561.855 us; speedup vs baseline: 1.1421x; 1.1421x over previous
//
#include <hip/hip_runtime.h>
#include <stdint.h>

#define S_ 1024
#define B_ 8
#define D_ 1024
#define H_ 16
#define DK_ 64
#define F_ 4096
#define EPS_ 1e-5f

typedef __bf16 bf16_t;
typedef __attribute__((ext_vector_type(8))) __bf16 bf16x8;
typedef __attribute__((ext_vector_type(4))) __bf16 bf16x4;
typedef __attribute__((ext_vector_type(4))) float f32x4;

// async global->LDS, 16B per lane; LDS dest must be wave-uniform base + lane*16
#define GLD16(gp, lp) __builtin_amdgcn_global_load_lds( \
    (__attribute__((address_space(1))) void*)(void*)(gp), \
    (__attribute__((address_space(3))) void*)(lp), 16, 0, 0)

#define BAR() __builtin_amdgcn_s_barrier()
#define SB0() __builtin_amdgcn_sched_barrier(0)
#define LG0() do { asm volatile("s_waitcnt lgkmcnt(0)" ::: "memory"); SB0(); } while (0)
#define VM6() asm volatile("s_waitcnt vmcnt(6)" ::: "memory")
#define VM4() asm volatile("s_waitcnt vmcnt(4)" ::: "memory")
#define VM3() asm volatile("s_waitcnt vmcnt(3)" ::: "memory")

// ---------------------------------------------------------------------------
// 8-phase 256x256 GEMM (T2+T3+T4+T5), C = A[M,K] * Bt[N,K]^T + bias.
// 512 threads = 8 waves (2 row-groups x 4 col-groups); per-wave 128x64 out.
// MODE 0: scatter to q/k bufs [B,H,S,DK] (col<1024 -> out/bias, else out2/bias2)
// MODE 1: relu -> bf16 row-major (ldc)
// ---------------------------------------------------------------------------
template<int MODE>
__global__ __launch_bounds__(512, 2)
void gemm8p(const bf16_t* __restrict__ A, const bf16_t* __restrict__ Bt,
            const float* __restrict__ bias, const float* __restrict__ bias2,
            void* __restrict__ out, void* __restrict__ out2,
            int K, int lda, int ldb, int ldc)
{
    __shared__ __align__(16) bf16_t AsL[2][256][64];
    __shared__ __align__(16) bf16_t BsL[2][256][64];

    const int nwg = gridDim.x * gridDim.y;
    int flat = blockIdx.y * gridDim.x + blockIdx.x;
    flat = (flat & 7) * (nwg >> 3) + (flat >> 3);
    const int bx = flat % gridDim.x, by = flat / gridDim.x;
    const int rowBase = by * 256, colBase = bx * 256;

    const int tid = threadIdx.x;
    const int lane = tid & 63;
    const int wave = tid >> 6;
    const int wr = wave >> 2, wc = wave & 3;
    const int lr = lane & 15, quad = lane >> 4;

    const int r0 = tid >> 3, r1 = 64 + r0;
    const int cs = (tid & 7) ^ (r0 & 7);
    const int cl = tid & 7;
    const bf16_t* a0p = A + (size_t)(rowBase + r0) * lda + cs * 8;
    const bf16_t* a1p = A + (size_t)(rowBase + r1) * lda + cs * 8;
    const bf16_t* b0p = Bt + (size_t)(colBase + r0) * ldb + cs * 8;
    const bf16_t* b1p = Bt + (size_t)(colBase + r1) * ldb + cs * 8;

#define STAGE_A(buf, h, kel) do { \
    GLD16(a0p + (size_t)(h) * 128 * lda + (kel), &AsL[buf][(h) * 128 + r0][cl * 8]); \
    GLD16(a1p + (size_t)(h) * 128 * lda + (kel), &AsL[buf][(h) * 128 + r1][cl * 8]); } while (0)
#define STAGE_B(buf, h, kel) do { \
    GLD16(b0p + (size_t)(h) * 128 * ldb + (kel), &BsL[buf][(h) * 128 + r0][cl * 8]); \
    GLD16(b1p + (size_t)(h) * 128 * ldb + (kel), &BsL[buf][(h) * 128 + r1][cl * 8]); } while (0)

#define RDA(buf, qm, AF) do { \
    _Pragma("unroll") for (int mi = 0; mi < 4; ++mi) { \
        const int r_ = (qm) * 128 + wr * 64 + mi * 16 + lr; \
        _Pragma("unroll") for (int kk = 0; kk < 2; ++kk) \
            AF[mi * 2 + kk] = *(const bf16x8*)&AsL[buf][r_][((kk * 4 + quad) ^ (lr & 7)) * 8]; } } while (0)
#define RDB(buf, qn, BF) do { \
    _Pragma("unroll") for (int ni = 0; ni < 2; ++ni) { \
        const int r_ = (qn) * 128 + wc * 32 + ni * 16 + lr; \
        _Pragma("unroll") for (int kk = 0; kk < 2; ++kk) \
            BF[ni * 2 + kk] = *(const bf16x8*)&BsL[buf][r_][((kk * 4 + quad) ^ (lr & 7)) * 8]; } } while (0)

#define MQ(qm, qn, AF, BF) do { \
    __builtin_amdgcn_s_setprio(1); \
    _Pragma("unroll") for (int kk = 0; kk < 2; ++kk) \
    _Pragma("unroll") for (int mi = 0; mi < 4; ++mi) \
    _Pragma("unroll") for (int ni = 0; ni < 2; ++ni) \
        acc[(qm) * 4 + mi][(qn) * 2 + ni] = __builtin_amdgcn_mfma_f32_16x16x32_bf16( \
            AF[mi * 2 + kk], BF[ni * 2 + kk], acc[(qm) * 4 + mi][(qn) * 2 + ni], 0, 0, 0); \
    __builtin_amdgcn_s_setprio(0); } while (0)

    f32x4 acc[8][4] = {};
    bf16x8 af[8], bq0[4], bq1[4];

    STAGE_A(0, 0, 0); STAGE_B(0, 0, 0); STAGE_B(0, 1, 0); STAGE_A(0, 1, 0);
    STAGE_A(1, 0, 64); STAGE_B(1, 0, 64); STAGE_B(1, 1, 64);
    VM6();
    BAR(); SB0();

    const int NT = K >> 6;
    const int kCap = K - 64;
    for (int it = 0; it < (NT >> 1); ++it) {
        const int kP1 = it * 128 + 64;
        int kN0 = it * 128 + 128; if (kN0 > kCap) kN0 = kCap;
        int kN1 = it * 128 + 192; if (kN1 > kCap) kN1 = kCap;

        // P1: T0 Q00
        RDA(0, 0, af); RDB(0, 0, bq0);
        STAGE_A(1, 1, kP1);
        BAR(); LG0();
        MQ(0, 0, af, bq0);
        BAR(); SB0();
        // P2: T0 Q01
        RDB(0, 1, bq1);
        STAGE_A(0, 0, kN0);
        BAR(); LG0();
        MQ(0, 1, af, bq1);
        BAR(); SB0();
        // P3: T0 Q11
        RDA(0, 1, af);
        STAGE_B(0, 0, kN0);
        BAR(); LG0();
        MQ(1, 1, af, bq1);
        BAR(); SB0();
        // P4: T0 Q10
        STAGE_B(0, 1, kN0);
        BAR(); SB0();
        MQ(1, 0, af, bq0);
        VM6();
        BAR(); SB0();
        // P5: T1 Q00
        RDA(1, 0, af); RDB(1, 0, bq0);
        STAGE_A(0, 1, kN0);
        BAR(); LG0();
        MQ(0, 0, af, bq0);
        BAR(); SB0();
        // P6: T1 Q01
        RDB(1, 1, bq1);
        STAGE_A(1, 0, kN1);
        BAR(); LG0();
        MQ(0, 1, af, bq1);
        BAR(); SB0();
        // P7: T1 Q11
        RDA(1, 1, af);
        STAGE_B(1, 0, kN1);
        BAR(); LG0();
        MQ(1, 1, af, bq1);
        BAR(); SB0();
        // P8: T1 Q10
        STAGE_B(1, 1, kN1);
        BAR(); SB0();
        MQ(1, 0, af, bq0);
        VM6();
        BAR(); SB0();
    }

#pragma unroll
    for (int mi = 0; mi < 8; ++mi) {
#pragma unroll
        for (int ni = 0; ni < 4; ++ni) {
            const int col = colBase + (ni >> 1) * 128 + wc * 32 + (ni & 1) * 16 + lr;
            float bv;
            if constexpr (MODE == 0) bv = (col < 1024) ? bias[col] : bias2[col - 1024];
            else bv = bias[col];
#pragma unroll
            for (int e = 0; e < 4; ++e) {
                const int row = rowBase + (mi >> 2) * 128 + wr * 64 + (mi & 3) * 16 + quad * 4 + e;
                const float v = acc[mi][ni][e] + bv;
                if constexpr (MODE == 0) {
                    const int sel = col >> 10, c10 = col & 1023;
                    const int s = row >> 3, b = row & 7, h = c10 >> 6, dk = c10 & 63;
                    bf16_t* dst = sel ? (bf16_t*)out2 : (bf16_t*)out;
                    dst[(((size_t)(b * 16 + h) * 1024 + s) << 6) + dk] = (bf16_t)v;
                } else {
                    ((bf16_t*)out)[(size_t)row * ldc + col] = (bf16_t)fmaxf(v, 0.f);
                }
            }
        }
    }
#undef STAGE_A
#undef STAGE_B
#undef RDA
#undef RDB
#undef MQ
}

// ---------------------------------------------------------------------------
// 4-phase 256x128 GEMM, same technique stack, for N=1024 shapes (grid 256).
// MODE 0: fp32 out row-major (ldc)
// MODE 2: bf16 out scattered to vt buf [B,H,DK,S]
// ---------------------------------------------------------------------------
template<int MODE>
__global__ __launch_bounds__(512, 2)
void gemm4p(const bf16_t* __restrict__ A, const bf16_t* __restrict__ Bt,
            const float* __restrict__ bias, void* __restrict__ out,
            int K, int lda, int ldb, int ldc)
{
    __shared__ __align__(16) bf16_t AsL[2][256][64];
    __shared__ __align__(16) bf16_t BsL[2][128][64];

    const int nwg = gridDim.x * gridDim.y;
    int flat = blockIdx.y * gridDim.x + blockIdx.x;
    flat = (flat & 7) * (nwg >> 3) + (flat >> 3);
    const int bx = flat % gridDim.x, by = flat / gridDim.x;
    const int rowBase = by * 256, colBase = bx * 128;

    const int tid = threadIdx.x;
    const int lane = tid & 63;
    const int wave = tid >> 6;
    const int wr = wave >> 2, wc = wave & 3;
    const int lr = lane & 15, quad = lane >> 4;

    const int r0 = tid >> 3, r1 = 64 + r0;
    const int cs = (tid & 7) ^ (r0 & 7);
    const int cl = tid & 7;
    const bf16_t* a0p = A + (size_t)(rowBase + r0) * lda + cs * 8;
    const bf16_t* a1p = A + (size_t)(rowBase + r1) * lda + cs * 8;
    const bf16_t* b0p = Bt + (size_t)(colBase + r0) * ldb + cs * 8;

#define STAGE_A(buf, h, kel) do { \
    GLD16(a0p + (size_t)(h) * 128 * lda + (kel), &AsL[buf][(h) * 128 + r0][cl * 8]); \
    GLD16(a1p + (size_t)(h) * 128 * lda + (kel), &AsL[buf][(h) * 128 + r1][cl * 8]); } while (0)
#define STAGE_B(buf, h, kel) \
    GLD16(b0p + (size_t)(h) * 64 * ldb + (kel), &BsL[buf][(h) * 64 + r0][cl * 8])

#define RDA(buf, qm, AF) do { \
    _Pragma("unroll") for (int mi = 0; mi < 4; ++mi) { \
        const int r_ = (qm) * 128 + wr * 64 + mi * 16 + lr; \
        _Pragma("unroll") for (int kk = 0; kk < 2; ++kk) \
            AF[mi * 2 + kk] = *(const bf16x8*)&AsL[buf][r_][((kk * 4 + quad) ^ (lr & 7)) * 8]; } } while (0)
#define RDBF(buf, BQ) do { \
    _Pragma("unroll") for (int qn = 0; qn < 2; ++qn) { \
        const int r_ = qn * 64 + wc * 16 + lr; \
        _Pragma("unroll") for (int kk = 0; kk < 2; ++kk) \
            BQ[qn * 2 + kk] = *(const bf16x8*)&BsL[buf][r_][((kk * 4 + quad) ^ (lr & 7)) * 8]; } } while (0)

#define MQA(qm) do { \
    __builtin_amdgcn_s_setprio(1); \
    _Pragma("unroll") for (int kk = 0; kk < 2; ++kk) \
    _Pragma("unroll") for (int mi = 0; mi < 4; ++mi) \
    _Pragma("unroll") for (int qn = 0; qn < 2; ++qn) \
        acc[(qm) * 4 + mi][qn] = __builtin_amdgcn_mfma_f32_16x16x32_bf16( \
            af[mi * 2 + kk], bq[qn * 2 + kk], acc[(qm) * 4 + mi][qn], 0, 0, 0); \
    __builtin_amdgcn_s_setprio(0); } while (0)

    f32x4 acc[8][2] = {};
    bf16x8 af[8], bq[4];

    STAGE_A(0, 0, 0); STAGE_B(0, 0, 0); STAGE_B(0, 1, 0); STAGE_A(0, 1, 0);
    STAGE_A(1, 0, 64); STAGE_B(1, 0, 64); STAGE_B(1, 1, 64);
    VM4();
    BAR(); SB0();

    const int NT = K >> 6;
    const int kCap = K - 64;
    for (int it = 0; it < (NT >> 1); ++it) {
        const int kP1 = it * 128 + 64;
        int kN0 = it * 128 + 128; if (kN0 > kCap) kN0 = kCap;
        int kN1 = it * 128 + 192; if (kN1 > kCap) kN1 = kCap;

        // P1: buf0 qm0
        RDA(0, 0, af); RDBF(0, bq);
        STAGE_A(1, 1, kP1);
        BAR(); LG0();
        MQA(0);
        BAR(); SB0();
        // P2: buf0 qm1
        RDA(0, 1, af);
        STAGE_A(0, 0, kN0); STAGE_B(0, 0, kN0);
        BAR(); LG0();
        MQA(1);
        VM3();
        BAR(); SB0();
        // P3: buf1 qm0
        RDA(1, 0, af); RDBF(1, bq);
        STAGE_B(0, 1, kN0); STAGE_A(0, 1, kN0);
        BAR(); LG0();
        MQA(0);
        BAR(); SB0();
        // P4: buf1 qm1
        RDA(1, 1, af);
        STAGE_A(1, 0, kN1); STAGE_B(1, 0, kN1); STAGE_B(1, 1, kN1);
        BAR(); LG0();
        MQA(1);
        VM4();
        BAR(); SB0();
    }

#pragma unroll
    for (int mi = 0; mi < 8; ++mi) {
#pragma unroll
        for (int ni = 0; ni < 2; ++ni) {
            const int col = colBase + ni * 64 + wc * 16 + lr;
            const float bv = bias[col];
#pragma unroll
            for (int e = 0; e < 4; ++e) {
                const int row = rowBase + (mi >> 2) * 128 + wr * 64 + (mi & 3) * 16 + quad * 4 + e;
                const float v = acc[mi][ni][e] + bv;
                if constexpr (MODE == 0) {
                    ((float*)out)[(size_t)row * ldc + col] = v;
                } else {
                    const int s = row >> 3, b = row & 7, h = col >> 6, dk = col & 63;
                    ((bf16_t*)out)[(((size_t)(b * 16 + h) * 64 + dk) << 10) + s] = (bf16_t)v;
                }
            }
        }
    }
#undef STAGE_A
#undef STAGE_B
#undef RDA
#undef RDBF
#undef MQA
}

// ---------------------------------------------------------------------------
// Fused attention: per block = one (b,h) z and 32 query rows (R3 structure).
// Single delta vs R3: attn row store is nontemporal (write-once stream).
// ---------------------------------------------------------------------------
__global__ __launch_bounds__(256)
void fused_attn(const bf16_t* __restrict__ qb, const bf16_t* __restrict__ kb,
                const bf16_t* __restrict__ vt, float* __restrict__ attn,
                bf16_t* __restrict__ ctx)
{
    __shared__ __align__(16) bf16_t Psh[32 * 1024];   // 64 KB, XOR-swizzled
    __shared__ float smax[4][32];
    __shared__ float ssum[4][32];

    int flat = blockIdx.y * 32 + blockIdx.x;
    flat = (flat & 7) * 512 + (flat >> 3);
    const int z = flat >> 5;                 // (b*16+h)
    const int qBase = (flat & 31) * 32;
    const int b = z >> 4, h = z & 15;
    const int tid = threadIdx.x;
    const int wave = tid >> 6, lane = tid & 63;
    const int lr = lane & 15, quad = lane >> 4;

    const bf16_t* Qz = qb + ((size_t)z << 16);   // [1024][64]
    const bf16_t* Kz = kb + ((size_t)z << 16);   // [1024][64]
    const bf16_t* Vz = vt + ((size_t)z << 16);   // [64][1024]
    float* Az = attn + ((size_t)z << 20);

    bf16x8 qf[2][2];
#pragma unroll
    for (int ni = 0; ni < 2; ++ni)
#pragma unroll
        for (int kk = 0; kk < 2; ++kk)
            qf[ni][kk] = *(const bf16x8*)(Qz + (size_t)(qBase + ni * 16 + lr) * 64 + kk * 32 + quad * 8);

    f32x4 acc[16][2] = {};
#pragma unroll
    for (int mi = 0; mi < 16; ++mi) {
        const bf16_t* kp = Kz + (size_t)(wave * 256 + mi * 16 + lr) * 64 + quad * 8;
        bf16x8 kf0 = *(const bf16x8*)kp;
        bf16x8 kf1 = *(const bf16x8*)(kp + 32);
#pragma unroll
        for (int ni = 0; ni < 2; ++ni) {
            acc[mi][ni] = __builtin_amdgcn_mfma_f32_16x16x32_bf16(kf0, qf[ni][0], acc[mi][ni], 0, 0, 0);
            acc[mi][ni] = __builtin_amdgcn_mfma_f32_16x16x32_bf16(kf1, qf[ni][1], acc[mi][ni], 0, 0, 0);
        }
    }

    float mloc[2];
#pragma unroll
    for (int ni = 0; ni < 2; ++ni) {
        float mx = acc[0][ni][0];
#pragma unroll
        for (int mi = 0; mi < 16; ++mi)
            mx = fmaxf(mx, fmaxf(fmaxf(acc[mi][ni][0], acc[mi][ni][1]),
                                 fmaxf(acc[mi][ni][2], acc[mi][ni][3])));
        mx = fmaxf(mx, __shfl_xor(mx, 16, 64));
        mx = fmaxf(mx, __shfl_xor(mx, 32, 64));
        mloc[ni] = mx;
    }
    if (quad == 0) { smax[wave][lr] = mloc[0]; smax[wave][16 + lr] = mloc[1]; }
    __syncthreads();

    float rs[2];
#pragma unroll
    for (int ni = 0; ni < 2; ++ni) {
        const int qh = ni * 16 + lr;
        const float mm = 0.125f * fmaxf(fmaxf(smax[0][qh], smax[1][qh]),
                                        fmaxf(smax[2][qh], smax[3][qh]));
        float s = 0.f;
#pragma unroll
        for (int mi = 0; mi < 16; ++mi)
#pragma unroll
            for (int e = 0; e < 4; ++e) {
                float p = __expf(fmaf(acc[mi][ni][e], 0.125f, -mm));
                acc[mi][ni][e] = p; s += p;
            }
        s += __shfl_xor(s, 16, 64);
        s += __shfl_xor(s, 32, 64);
        rs[ni] = s;
    }
    if (quad == 0) { ssum[wave][lr] = rs[0]; ssum[wave][16 + lr] = rs[1]; }
    __syncthreads();

#pragma unroll
    for (int ni = 0; ni < 2; ++ni) {
        const int qh = ni * 16 + lr;
        const float r = 1.0f / (ssum[0][qh] + ssum[1][qh] + ssum[2][qh] + ssum[3][qh]);
        float* arow = Az + ((size_t)(qBase + qh) << 10);
#pragma unroll
        for (int mi = 0; mi < 16; ++mi) {
            const int k0 = wave * 256 + mi * 16 + quad * 4;
            f32x4 o;
            o[0] = acc[mi][ni][0] * r; o[1] = acc[mi][ni][1] * r;
            o[2] = acc[mi][ni][2] * r; o[3] = acc[mi][ni][3] * r;
            __builtin_nontemporal_store(o, (f32x4*)(arow + k0)); // write-once stream
            bf16x4 pb;
            pb[0] = (bf16_t)o[0]; pb[1] = (bf16_t)o[1]; pb[2] = (bf16_t)o[2]; pb[3] = (bf16_t)o[3];
            int byte = qh * 2048 + k0 * 2;
            byte ^= (qh & 7) << 4;
            *(bf16x4*)((char*)Psh + byte) = pb;
        }
    }
    __syncthreads();

    f32x4 cacc[2] = {};
#pragma unroll
    for (int kt = 0; kt < 32; ++kt) {
        bf16x8 vf = *(const bf16x8*)(Vz + (size_t)(wave * 16 + lr) * 1024 + kt * 32 + quad * 8);
#pragma unroll
        for (int mi = 0; mi < 2; ++mi) {
            const int qh = mi * 16 + lr;
            int byte = qh * 2048 + (kt * 32 + quad * 8) * 2;
            byte ^= (qh & 7) << 4;
            bf16x8 af = *(const bf16x8*)((const char*)Psh + byte);
            cacc[mi] = __builtin_amdgcn_mfma_f32_16x16x32_bf16(af, vf, cacc[mi], 0, 0, 0);
        }
    }
#pragma unroll
    for (int mi = 0; mi < 2; ++mi)
#pragma unroll
        for (int e = 0; e < 4; ++e) {
            const int s = qBase + mi * 16 + quad * 4 + e;
            ctx[(((size_t)s * 8 + b) << 10) + h * 64 + wave * 16 + lr] = (bf16_t)cacc[mi][e];
        }
}

__global__ __launch_bounds__(256)
void prep_kernel(const float* __restrict__ src, const float* __restrict__ pos,
                 bf16_t* __restrict__ qk, bf16_t* __restrict__ vv)
{
    const size_t i = ((size_t)blockIdx.x * 256 + threadIdx.x) * 4;
    float4 s = *(const float4*)(src + i);
    float4 q = *(const float4*)(pos + i);
    bf16x4 qo, vo;
    qo[0] = (bf16_t)(s.x + q.x); qo[1] = (bf16_t)(s.y + q.y);
    qo[2] = (bf16_t)(s.z + q.z); qo[3] = (bf16_t)(s.w + q.w);
    vo[0] = (bf16_t)s.x; vo[1] = (bf16_t)s.y; vo[2] = (bf16_t)s.z; vo[3] = (bf16_t)s.w;
    *(bf16x4*)(qk + i) = qo;
    *(bf16x4*)(vv + i) = vo;
}

// z-batched: four 1024x1024 fp32 W -> bf16 WT [N,K]
__global__ __launch_bounds__(256)
void transpose_w4(const float* __restrict__ W0, const float* __restrict__ W1,
                  const float* __restrict__ W2, const float* __restrict__ W3,
                  bf16_t* __restrict__ T0, bf16_t* __restrict__ T1,
                  bf16_t* __restrict__ T2, bf16_t* __restrict__ T3)
{
    __shared__ float t[32][33];
    const float* W; bf16_t* T;
    switch (blockIdx.z) {
        case 0: W = W0; T = T0; break;
        case 1: W = W1; T = T1; break;
        case 2: W = W2; T = T2; break;
        default: W = W3; T = T3; break;
    }
    const int n0 = blockIdx.x * 32, k0 = blockIdx.y * 32;
    const int tx = threadIdx.x & 31;
    const int ty = threadIdx.x >> 5;
#pragma unroll
    for (int j = 0; j < 32; j += 8)
        t[ty + j][tx] = W[(size_t)(k0 + ty + j) * 1024 + n0 + tx];
    __syncthreads();
#pragma unroll
    for (int j = 0; j < 32; j += 8)
        T[(size_t)(n0 + ty + j) * 1024 + k0 + tx] = (bf16_t)t[tx][ty + j];
}

// W fp32 [K,N] row-major -> WT bf16 [N,K]
__global__ __launch_bounds__(256)
void transpose_w(const float* __restrict__ W, bf16_t* __restrict__ WT, int K, int N)
{
    __shared__ float t[32][33];
    const int n0 = blockIdx.x * 32, k0 = blockIdx.y * 32;
    const int tx = threadIdx.x & 31;
    const int ty = threadIdx.x >> 5;
#pragma unroll
    for (int j = 0; j < 32; j += 8)
        t[ty + j][tx] = W[(size_t)(k0 + ty + j) * N + n0 + tx];
    __syncthreads();
#pragma unroll
    for (int j = 0; j < 32; j += 8)
        WT[(size_t)(n0 + ty + j) * K + k0 + tx] = (bf16_t)t[tx][ty + j];
}

// LN over D=1024 of (a+b); writes any of xf (fp32), xb (bf16), outf (fp32)
__global__ __launch_bounds__(256)
void ln_kernel(const float* __restrict__ a, const float* __restrict__ b,
               const float* __restrict__ g, const float* __restrict__ be,
               float* __restrict__ xf, bf16_t* __restrict__ xb, float* __restrict__ outf)
{
    __shared__ float sh[8];
    const int r = blockIdx.x;
    const int t = threadIdx.x;
    float4 va = ((const float4*)(a + ((size_t)r << 10)))[t];
    float4 vb = ((const float4*)(b + ((size_t)r << 10)))[t];
    float x0 = va.x + vb.x, x1 = va.y + vb.y, x2 = va.z + vb.z, x3 = va.w + vb.w;
    float s = x0 + x1 + x2 + x3;
    float sq = x0 * x0 + x1 * x1 + x2 * x2 + x3 * x3;
#pragma unroll
    for (int o = 32; o > 0; o >>= 1) { s += __shfl_xor(s, o, 64); sq += __shfl_xor(sq, o, 64); }
    const int w = t >> 6, ln = t & 63;
    if (ln == 0) { sh[w] = s; sh[4 + w] = sq; }
    __syncthreads();
    s = sh[0] + sh[1] + sh[2] + sh[3];
    sq = sh[4] + sh[5] + sh[6] + sh[7];
    const float mean = s * (1.f / 1024.f);
    const float var = sq * (1.f / 1024.f) - mean * mean;
    const float rstd = rsqrtf(var + EPS_);
    float4 vg = ((const float4*)g)[t];
    float4 vbe = ((const float4*)be)[t];
    float y0 = (x0 - mean) * rstd * vg.x + vbe.x;
    float y1 = (x1 - mean) * rstd * vg.y + vbe.y;
    float y2 = (x2 - mean) * rstd * vg.z + vbe.z;
    float y3 = (x3 - mean) * rstd * vg.w + vbe.w;
    if (xf) { float4 o4 = {y0, y1, y2, y3}; ((float4*)(xf + ((size_t)r << 10)))[t] = o4; }
    if (xb) {
        bf16x4 ob; ob[0] = (bf16_t)y0; ob[1] = (bf16_t)y1; ob[2] = (bf16_t)y2; ob[3] = (bf16_t)y3;
        ((bf16x4*)(xb + ((size_t)r << 10)))[t] = ob;
    }
    if (outf) { float4 o4 = {y0, y1, y2, y3}; ((float4*)(outf + ((size_t)r << 10)))[t] = o4; }
}

extern "C" void kernel_launch(void* const* d_in, const int* in_sizes, int n_in,
                              void* d_out, int out_size, void* d_ws, size_t ws_size,
                              hipStream_t stream)
{
    (void)in_sizes; (void)n_in; (void)out_size; (void)ws_size;
    const float* src = (const float*)d_in[0];
    const float* pos = (const float*)d_in[1];
    const float* Wq  = (const float*)d_in[2];
    const float* bq  = (const float*)d_in[3];
    const float* Wk  = (const float*)d_in[4];
    const float* bk  = (const float*)d_in[5];
    const float* Wv  = (const float*)d_in[6];
    const float* bv  = (const float*)d_in[7];
    const float* Wo  = (const float*)d_in[8];
    const float* bo  = (const float*)d_in[9];
    const float* W1  = (const float*)d_in[10];
    const float* b1  = (const float*)d_in[11];
    const float* W2  = (const float*)d_in[12];
    const float* b2  = (const float*)d_in[13];
    const float* g1  = (const float*)d_in[14];
    const float* be1 = (const float*)d_in[15];
    const float* g2  = (const float*)d_in[16];
    const float* be2 = (const float*)d_in[17];

    float* outF  = (float*)d_out;                       // [S,B,D]
    float* attnF = outF + (size_t)S_ * B_ * D_;         // [B,H,S,S]

    char* ws = (char*)d_ws;
    size_t off = 0;
    auto alloc = [&](size_t bytes) { void* p = ws + off; off += (bytes + 255) & ~(size_t)255; return p; };

    bf16_t* qk_bf = (bf16_t*)alloc((size_t)8192 * 1024 * 2);
    bf16_t* v_bf  = (bf16_t*)alloc((size_t)8192 * 1024 * 2);
    bf16_t* wqT   = (bf16_t*)alloc((size_t)1024 * 1024 * 2);   // wqT/wkT contiguous ->
    bf16_t* wkT   = (bf16_t*)alloc((size_t)1024 * 1024 * 2);   // one [2048,1024] B for QK
    bf16_t* wvT   = (bf16_t*)alloc((size_t)1024 * 1024 * 2);
    bf16_t* woT   = (bf16_t*)alloc((size_t)1024 * 1024 * 2);
    bf16_t* w1T   = (bf16_t*)alloc((size_t)4096 * 1024 * 2);
    bf16_t* w2T   = (bf16_t*)alloc((size_t)1024 * 4096 * 2);
    bf16_t* qbuf  = (bf16_t*)alloc((size_t)8 * 16 * 1024 * 64 * 2);
    bf16_t* kbuf  = (bf16_t*)alloc((size_t)8 * 16 * 1024 * 64 * 2);
    bf16_t* vtbuf = (bf16_t*)alloc((size_t)8 * 16 * 64 * 1024 * 2);
    bf16_t* ctx_bf= (bf16_t*)alloc((size_t)8192 * 1024 * 2);
    float*  ao_f  = (float*)alloc((size_t)8192 * 1024 * 4);
    float*  x_f   = (float*)alloc((size_t)8192 * 1024 * 4);
    bf16_t* x_bf  = (bf16_t*)alloc((size_t)8192 * 1024 * 2);
    bf16_t* h_bf  = (bf16_t*)alloc((size_t)8192 * 4096 * 2);
    float*  y_f   = (float*)alloc((size_t)8192 * 1024 * 4);

    // weights -> bf16 transposed [N,K]
    transpose_w4<<<dim3(32, 32, 4), 256, 0, stream>>>(Wq, Wk, Wv, Wo, wqT, wkT, wvT, woT);
    transpose_w<<<dim3(128, 32), 256, 0, stream>>>(W1, w1T, 1024, 4096);
    transpose_w<<<dim3(32, 128), 256, 0, stream>>>(W2, w2T, 4096, 1024);

    prep_kernel<<<8192, 256, 0, stream>>>(src, pos, qk_bf, v_bf);

    // Q+K combined projection (8-phase 256^2): N=2048 over [wqT;wkT]
    gemm8p<0><<<dim3(8, 32), 512, 0, stream>>>(qk_bf, wqT, bq, bk, qbuf, kbuf, 1024, 1024, 1024, 0);
    // V projection (4-phase 256x128)
    gemm4p<2><<<dim3(8, 32), 512, 0, stream>>>(v_bf, wvT, bv, vtbuf, 1024, 1024, 1024, 0);

    // fused scores -> softmax -> attn write (NT) -> PV
    fused_attn<<<dim3(32, 128), 256, 0, stream>>>(qbuf, kbuf, vtbuf, attnF, ctx_bf);

    // attn_out = ctx @ Wo + bo (4-phase 256x128)
    gemm4p<0><<<dim3(8, 32), 512, 0, stream>>>(ctx_bf, woT, bo, ao_f, 1024, 1024, 1024, 1024);

    // x = LN(src + attn_out)
    ln_kernel<<<8192, 256, 0, stream>>>(src, ao_f, g1, be1, x_f, x_bf, nullptr);

    // ffn: h = relu(x @ W1 + b1)  (8-phase 256^2)
    gemm8p<1><<<dim3(16, 32), 512, 0, stream>>>(x_bf, w1T, b1, nullptr, h_bf, nullptr, 1024, 1024, 1024, 4096);
    // y = h @ W2 + b2 (4-phase 256x128, K=4096)
    gemm4p<0><<<dim3(8, 32), 512, 0, stream>>>(h_bf, w2T, b2, y_f, 4096, 4096, 4096, 1024);

    // out = LN(x + ffn)
    ln_kernel<<<8192, 256, 0, stream>>>(x_f, y_f, g2, be2, nullptr, nullptr, outF);
}